// Round 18
// baseline (231.911 us; speedup 1.0000x reference)
//
#include <hip/hip_runtime.h>
#include <hip/hip_bf16.h>

#define LL 2048
#define DD 128
#define NB 32
#define SCALE 0.08838834764831845f
#define C1 (SCALE * 1.4426950408889634f)   // scale * log2(e)

typedef short short8 __attribute__((ext_vector_type(8)));
typedef float f32x4 __attribute__((ext_vector_type(4)));
typedef float f32x16 __attribute__((ext_vector_type(16)));
typedef int int4v __attribute__((ext_vector_type(4)));
typedef unsigned int uint2v __attribute__((ext_vector_type(2)));

__device__ __forceinline__ unsigned int pkbf(float lo, float hi) {
  __hip_bfloat162 h = __float22bfloat162_rn(make_float2(lo, hi));
  union { __hip_bfloat162 h2; unsigned int u; } c;
  c.h2 = h;
  return c.u;
}

__device__ __forceinline__ void load_lds16(const void* g, void* l) {
  __builtin_amdgcn_global_load_lds(
      (const __attribute__((address_space(1))) unsigned int*)g,
      (__attribute__((address_space(3))) unsigned int*)l, 16, 0, 0);
}

// ============================================================================
// One-shot converter: K / V^T -> bf16 tiles in d_ws.
// Tile = 64 keys x 128 d (16384 B). K: 16-slot swizzle g^(key&15).
// V: [d][key ^ ((d&7)<<3)].
// ============================================================================
__global__ __launch_bounds__(256) void convKV(const float* __restrict__ k,
                                              const float* __restrict__ v,
                                              unsigned short* __restrict__ wsK,
                                              unsigned short* __restrict__ wsV) {
  __shared__ float lt[64][132];
  if (blockIdx.x < NB * 32) {
    const int t = blockIdx.x;
    const float* src = k + (size_t)t * 8192;
    unsigned short* dst = wsK + (size_t)t * 8192;
    const int key = threadIdx.x >> 2, dq = (threadIdx.x & 3) * 32;
    const float* row = src + key * 128 + dq;
    unsigned short* drow = dst + key * 128;
#pragma unroll
    for (int g = 0; g < 4; ++g) {
      f32x4 a = *(const f32x4*)(row + g * 8);
      f32x4 b2 = *(const f32x4*)(row + g * 8 + 4);
      int4v y = {(int)pkbf(a[0], a[1]), (int)pkbf(a[2], a[3]),
                 (int)pkbf(b2[0], b2[1]), (int)pkbf(b2[2], b2[3])};
      const int gi = (((dq >> 3) + g) ^ (key & 15));
      *(int4v*)(drow + gi * 8) = y;
    }
  } else {
    const int t = blockIdx.x - NB * 32;
    const float* src = v + (size_t)t * 8192;
    unsigned short* dst = wsV + (size_t)t * 8192;
    const int key = threadIdx.x >> 2, dq = (threadIdx.x & 3) * 32;
#pragma unroll
    for (int g = 0; g < 8; ++g)
      *(f32x4*)&lt[key][dq + g * 4] = *(const f32x4*)(src + key * 128 + dq + g * 4);
    __syncthreads();
    const int d = threadIdx.x >> 1, kh = (threadIdx.x & 1) * 32;
    unsigned short* drow = dst + d * 64;
#pragma unroll
    for (int g = 0; g < 4; ++g) {
      const int k0 = kh + g * 8;
      int4v y = {(int)pkbf(lt[k0 + 0][d], lt[k0 + 1][d]),
                 (int)pkbf(lt[k0 + 2][d], lt[k0 + 3][d]),
                 (int)pkbf(lt[k0 + 4][d], lt[k0 + 5][d]),
                 (int)pkbf(lt[k0 + 6][d], lt[k0 + 7][d])};
      const int gi = ((k0 >> 3) ^ (d & 7));
      *(int4v*)(drow + gi * 8) = y;
    }
  }
}

// ============================================================================
// Main fused kernel — r16 structure; pass-2 stores reordered ROW-MAJOR:
// compute all 8 groups of a 256-key chunk, then per output row issue 8
// consecutive 128B segments -> L2 merges into ~1KB HBM bursts.
// ============================================================================
__global__ __launch_bounds__(512, 2) void attn_fused2(
    const float* __restrict__ q, const unsigned short* __restrict__ wsK,
    const unsigned short* __restrict__ wsV, float* out) {
  __shared__ __align__(16) unsigned short smem[65536];   // 128 KB

  const int tid = threadIdx.x;
  const int w = tid >> 6, l = tid & 63;                  // 8 waves
  const int qi = l & 31, hi = l >> 5;
  const unsigned swzv = (l & 7) << 3;                    // V: 8-slot
  const unsigned swzk = (l & 15) << 3;                   // K: 16-slot

  const int i0 = blockIdx.x;             // 256 blocks, 1 per CU
  const int xcd = i0 & 7, j = i0 >> 3;   // 4 batches per XCD
  const int b = xcd + 8 * (j >> 3);
  const int qx8 = j & 7;
  const int qw = qx8 * 256 + w * 32;     // 8 waves cover 256 q-rows

  const float* qb_ = q + (size_t)b * LL * DD;
  float* ctxW = out + ((size_t)b * LL + qw) * DD;
  float* attnW = out + (size_t)NB * LL * DD + ((size_t)b * LL + qw) * (size_t)LL;

  const char* wsKb = (const char*)wsK + (size_t)b * 32 * 16384;
  const char* wsVb = (const char*)wsV + (size_t)b * 32 * 16384;

  unsigned short* kT0 = smem;            // pass 1: 2 x 32 KB K chunks
  unsigned short* vT0 = smem + 32768;    // pass 1: 2 x 32 KB V chunks

#define STAGE32(srcb, ldsb)                                       \
  {                                                               \
    _Pragma("unroll") for (int i_ = 0; i_ < 4; ++i_) {            \
      const int o_ = i_ * 8192 + w * 1024;                        \
      load_lds16((const char*)(srcb) + o_ + l * 16,               \
                 (char*)(ldsb) + o_);                             \
    }                                                             \
  }

  // ---- Q fragments: lane holds Q[qw+qi][dt*16 + hi*8 + j] ----
  short8 aq[8];
  {
    const float* qrow = qb_ + (size_t)(qw + qi) * DD + hi * 8;
#pragma unroll
    for (int dt = 0; dt < 8; ++dt) {
      f32x4 x0 = *(const f32x4*)(qrow + dt * 16);
      f32x4 x1 = *(const f32x4*)(qrow + dt * 16 + 4);
      int4v pw = {(int)pkbf(x0[0], x0[1]), (int)pkbf(x0[2], x0[3]),
                  (int)pkbf(x1[0], x1[1]), (int)pkbf(x1[2], x1[3])};
      aq[dt] = __builtin_bit_cast(short8, pw);
    }
  }

  float s = 0.f;
  f32x16 apv[4];
#pragma unroll
  for (int nt = 0; nt < 4; ++nt)
    apv[nt] = (f32x16){0.f,0.f,0.f,0.f,0.f,0.f,0.f,0.f,0.f,0.f,0.f,0.f,0.f,0.f,0.f,0.f};

  // =================== pass 1: flash (swapped QK + PV) ===================
  STAGE32(wsKb, (char*)kT0);
  STAGE32(wsVb, (char*)vT0);
  asm volatile("s_waitcnt vmcnt(0)" ::: "memory");
  __builtin_amdgcn_s_barrier();
  asm volatile("" ::: "memory");

  int cur = 0;
  for (int kc = 0; kc < 16; ++kc) {      // 128-key chunks
    if (kc + 1 < 16) {
      STAGE32(wsKb + (kc + 1) * 32768, (char*)(kT0 + (cur ^ 1) * 16384));
      STAGE32(wsVb + (kc + 1) * 32768, (char*)(vT0 + (cur ^ 1) * 16384));
    }
    const unsigned short* kTc = kT0 + cur * 16384;
    const unsigned short* vTc = vT0 + cur * 16384;
#pragma unroll
    for (int t = 0; t < 4; ++t) {        // four 32-key groups per chunk
      const int tile = t >> 1, tt = t & 1;
      f32x16 acc = (f32x16){0.f,0.f,0.f,0.f,0.f,0.f,0.f,0.f,0.f,0.f,0.f,0.f,0.f,0.f,0.f,0.f};
      const int arow = tile * 8192 + (tt * 32 + qi) * DD;
      __builtin_amdgcn_s_setprio(1);
#pragma unroll
      for (int dt = 0; dt < 8; ++dt) {
        short8 ka = *(const short8*)&kTc[arow + ((dt * 16 + hi * 8) ^ swzk)];
        acc = __builtin_amdgcn_mfma_f32_32x32x16_bf16(ka, aq[dt], acc, 0, 0, 0);
      }
      __builtin_amdgcn_s_setprio(0);

      float p[16];
#pragma unroll
      for (int r = 0; r < 16; ++r) {
        p[r] = __builtin_amdgcn_exp2f(acc[r] * C1);   // unnormalized, <= ~500
        s += p[r];
      }

#pragma unroll
      for (int kt2 = 0; kt2 < 2; ++kt2) {
        const int p0 = kt2 * 8;
        unsigned a0 = pkbf(p[p0 + 0], p[p0 + 1]);
        unsigned a1 = pkbf(p[p0 + 2], p[p0 + 3]);
        unsigned b0 = pkbf(p[p0 + 4], p[p0 + 5]);
        unsigned b1 = pkbf(p[p0 + 6], p[p0 + 7]);
        unsigned a0s = (unsigned)__shfl_xor((int)a0, 32);
        unsigned a1s = (unsigned)__shfl_xor((int)a1, 32);
        unsigned b0s = (unsigned)__shfl_xor((int)b0, 32);
        unsigned b1s = (unsigned)__shfl_xor((int)b1, 32);
        unsigned w0 = hi ? b0s : a0;
        unsigned w1 = hi ? b1s : a1;
        unsigned w2 = hi ? b0 : a0s;
        unsigned w3 = hi ? b1 : a1s;
        int4v pw = {(int)w0, (int)w1, (int)w2, (int)w3};
        short8 pa = __builtin_bit_cast(short8, pw);

        const int vbase = tile * 8192;
        const int vc = ((tt * 32 + kt2 * 16 + hi * 8) ^ swzv);
        __builtin_amdgcn_s_setprio(1);
#pragma unroll
        for (int nt = 0; nt < 4; ++nt) {
          short8 bv = *(const short8*)&vTc[vbase + (nt * 32 + qi) * 64 + vc];
          apv[nt] = __builtin_amdgcn_mfma_f32_32x32x16_bf16(pa, bv, apv[nt], 0, 0, 0);
        }
        __builtin_amdgcn_s_setprio(0);
      }
    }
    asm volatile("s_waitcnt vmcnt(0) lgkmcnt(0)" ::: "memory");
    __builtin_amdgcn_s_barrier();
    asm volatile("" ::: "memory");
    cur ^= 1;
  }

  // ---- softmax denominators ----
  s += __shfl_xor(s, 32);                      // denominator for q-row qi
  const float rinv = 1.0f / s;
  const float nls = -__builtin_amdgcn_logf(s); // -log2(sum)
  float nlsr[16], invr[16];
#pragma unroll
  for (int r = 0; r < 16; ++r) {
    const int row = (r & 3) + 8 * (r >> 2) + 4 * hi;
    nlsr[r] = __shfl(nls, row);
    invr[r] = __shfl(rinv, row);
  }

  // =================== pass 2 prologue ===================
  unsigned short* h0 = smem;             // 64 KB half = 256 keys (4 tiles)
  unsigned short* h1 = smem + 32768;

#define STAGE64(c, halfp)                                                    \
  {                                                                          \
    _Pragma("unroll") for (int i_ = 0; i_ < 8; ++i_) {                       \
      const int o_ = i_ * 8192 + w * 1024;                                   \
      load_lds16(wsKb + (size_t)(c) * 65536 + o_ + l * 16,                   \
                 (char*)(halfp) + o_);                                       \
    }                                                                        \
  }

  STAGE64(0, h0);   // DMA hides under the ctx stores below

  // ---- context store (64 stores/thread, issued after the 8 DMA) ----
#pragma unroll
  for (int nt = 0; nt < 4; ++nt)
#pragma unroll
    for (int r = 0; r < 16; ++r) {
      const int row = (r & 3) + 8 * (r >> 2) + 4 * hi;
      ctxW[(size_t)row * DD + nt * 32 + qi] = apv[nt][r] * invr[r];
    }

  asm volatile("s_waitcnt vmcnt(48) lgkmcnt(0)" ::: "memory");
  __builtin_amdgcn_s_barrier();
  asm volatile("" ::: "memory");

  // =================== pass 2: attn write (normal QK, row-major stores) ===
  for (int c = 0; c < 8; ++c) {          // 256-key chunks
    unsigned short* curh = (c & 1) ? h1 : h0;
    unsigned short* nxth = (c & 1) ? h0 : h1;
    if (c + 1 < 8) STAGE64(c + 1, nxth);

    // ---- compute ALL 8 groups of this chunk into registers ----
    f32x16 acc8[8];
#pragma unroll
    for (int g = 0; g < 8; ++g) {        // eight 32-key groups per chunk
      const int tile = g >> 1, tt = g & 1;
      const unsigned short* kTc = curh + tile * 8192;
      f32x16 acc = (f32x16){0.f,0.f,0.f,0.f,0.f,0.f,0.f,0.f,0.f,0.f,0.f,0.f,0.f,0.f,0.f,0.f};
      const int arow = (tt * 32 + qi) * DD;
      __builtin_amdgcn_s_setprio(1);
#pragma unroll
      for (int dt = 0; dt < 8; ++dt) {
        short8 ka = *(const short8*)&kTc[arow + ((dt * 16 + hi * 8) ^ swzk)];
        acc = __builtin_amdgcn_mfma_f32_32x32x16_bf16(aq[dt], ka, acc, 0, 0, 0);
      }
      __builtin_amdgcn_s_setprio(0);
      acc8[g] = acc;
    }

    // ---- row-major store: per row, 8 consecutive 128B segments ----
    // acc8[g][r]: q-row (r&3)+8*(r>>2)+4*hi, key c*256 + g*32 + qi
    float* dstc = attnW + c * 256 + qi;
#pragma unroll
    for (int r = 0; r < 16; ++r) {
      const int row = (r & 3) + 8 * (r >> 2) + 4 * hi;
      float* dr = dstc + (size_t)row * LL;
#pragma unroll
      for (int g = 0; g < 8; ++g)
        dr[g * 32] = __builtin_amdgcn_exp2f(__builtin_fmaf(acc8[g][r], C1, nlsr[r]));
    }

    // 128 stores issued after this chunk's 8 DMA -> vmcnt(48) retires the DMA
    // without draining the store stream.
    asm volatile("s_waitcnt vmcnt(48) lgkmcnt(0)" ::: "memory");
    __builtin_amdgcn_s_barrier();
    asm volatile("" ::: "memory");
  }
#undef STAGE64
#undef STAGE32
}

// ============================================================================
// Fallback path (round-8, used only if ws_size too small)
// ============================================================================
__global__ __launch_bounds__(128, 2) void attn_ctx(
    const float* __restrict__ q, const float* __restrict__ k,
    const float* __restrict__ v, float* out) {
  __shared__ __align__(16) unsigned short kT[2][32 * DD];
  __shared__ __align__(16) unsigned short vT[2][DD * 32];
  const int tid = threadIdx.x;
  const int w = tid >> 6, l = tid & 63;
  const int qi = l & 31, hi = l >> 5;
  const unsigned swz = (l & 7) << 3;
  const int i0 = blockIdx.x;
  const int b = (i0 & 7) + 8 * (i0 >> 8);
  const int qx = (i0 >> 3) & 31;
  const int qw = qx * 64 + w * 32;
  const float* qb_ = q + (size_t)b * LL * DD;
  const float* kb_ = k + (size_t)b * LL * DD;
  const float* vb_ = v + (size_t)b * LL * DD;
  float* ctxW = out + ((size_t)b * LL + qw) * DD;
  float* sumPtr = out + (size_t)NB * LL * DD + ((size_t)b * LL + qw + qi) * LL + (LL - 1);
  const int kr = tid >> 5, kc4 = tid & 31;
  const int vk0 = (tid & 7) * 4, vd0 = (tid >> 3) * 8;
  short8 aq[8];
  {
    const float* qrow = qb_ + (size_t)(qw + qi) * DD + hi * 8;
#pragma unroll
    for (int dt = 0; dt < 8; ++dt) {
      f32x4 x0 = *(const f32x4*)(qrow + dt * 16);
      f32x4 x1 = *(const f32x4*)(qrow + dt * 16 + 4);
      int4v pw = {(int)pkbf(x0[0], x0[1]), (int)pkbf(x0[2], x0[3]),
                  (int)pkbf(x1[0], x1[1]), (int)pkbf(x1[2], x1[3])};
      aq[dt] = __builtin_bit_cast(short8, pw);
    }
  }
  f32x4 pk[8], pv[8];
  auto loadK = [&](int kc) {
#pragma unroll
    for (int j2 = 0; j2 < 8; ++j2)
      pk[j2] = *(const f32x4*)(kb_ + (size_t)(kc * 32 + kr + 4 * j2) * DD + kc4 * 4);
  };
  auto writeK = [&](int buf) {
#pragma unroll
    for (int j2 = 0; j2 < 8; ++j2) {
      const int r = kr + 4 * j2;
      uint2v y = {pkbf(pk[j2][0], pk[j2][1]), pkbf(pk[j2][2], pk[j2][3])};
      *(uint2v*)&kT[buf][r * DD + ((kc4 * 4) ^ ((r & 7) << 3))] = y;
    }
  };
  auto loadV = [&](int kc) {
#pragma unroll
    for (int i = 0; i < 4; ++i)
#pragma unroll
      for (int h = 0; h < 2; ++h)
        pv[i * 2 + h] = *(const f32x4*)(vb_ + (size_t)(kc * 32 + vk0 + i) * DD + vd0 + h * 4);
  };
  auto writeV = [&](int buf) {
#pragma unroll
    for (int dd = 0; dd < 8; ++dd) {
      const int h = dd >> 2, c = dd & 3;
      const int r = vd0 + dd;
      uint2v y = {pkbf(pv[0 + h][c], pv[2 + h][c]), pkbf(pv[4 + h][c], pv[6 + h][c])};
      *(uint2v*)&vT[buf][r * 32 + (vk0 ^ ((r & 3) << 3))] = y;
    }
  };
  float s = 0.f;
  f32x16 apv[4];
#pragma unroll
  for (int nt = 0; nt < 4; ++nt)
    apv[nt] = (f32x16){0.f,0.f,0.f,0.f,0.f,0.f,0.f,0.f,0.f,0.f,0.f,0.f,0.f,0.f,0.f,0.f};
  loadK(0); loadV(0); writeK(0); writeV(0);
  asm volatile("s_waitcnt lgkmcnt(0)" ::: "memory");
  __builtin_amdgcn_s_barrier();
  asm volatile("" ::: "memory");
  int cur = 0;
  for (int kc = 0; kc < 64; ++kc) {
    if (kc + 1 < 64) { loadK(kc + 1); loadV(kc + 1); }
    f32x16 acc = (f32x16){0.f,0.f,0.f,0.f,0.f,0.f,0.f,0.f,0.f,0.f,0.f,0.f,0.f,0.f,0.f,0.f};
    __builtin_amdgcn_s_setprio(1);
#pragma unroll
    for (int dt = 0; dt < 8; ++dt) {
      short8 ka = *(const short8*)&kT[cur][qi * DD + ((dt * 16 + hi * 8) ^ swz)];
      acc = __builtin_amdgcn_mfma_f32_32x32x16_bf16(ka, aq[dt], acc, 0, 0, 0);
    }
    __builtin_amdgcn_s_setprio(0);
    float p[16];
#pragma unroll
    for (int r = 0; r < 16; ++r) { p[r] = __builtin_amdgcn_exp2f(acc[r] * C1); s += p[r]; }
#pragma unroll
    for (int kt2 = 0; kt2 < 2; ++kt2) {
      const int p0 = kt2 * 8;
      unsigned a0 = pkbf(p[p0 + 0], p[p0 + 1]);
      unsigned a1 = pkbf(p[p0 + 2], p[p0 + 3]);
      unsigned b0 = pkbf(p[p0 + 4], p[p0 + 5]);
      unsigned b1 = pkbf(p[p0 + 6], p[p0 + 7]);
      unsigned a0s = (unsigned)__shfl_xor((int)a0, 32);
      unsigned a1s = (unsigned)__shfl_xor((int)a1, 32);
      unsigned b0s = (unsigned)__shfl_xor((int)b0, 32);
      unsigned b1s = (unsigned)__shfl_xor((int)b1, 32);
      unsigned w0 = hi ? b0s : a0;
      unsigned w1 = hi ? b1s : a1;
      unsigned w2 = hi ? b0 : a0s;
      unsigned w3 = hi ? b1 : a1s;
      int4v pw = {(int)w0, (int)w1, (int)w2, (int)w3};
      short8 pa = __builtin_bit_cast(short8, pw);
      const int vcol = (kt2 * 16 + hi * 8) ^ ((qi & 3) << 3);
      __builtin_amdgcn_s_setprio(1);
#pragma unroll
      for (int nt = 0; nt < 4; ++nt) {
        short8 bv = *(const short8*)&vT[cur][(nt * 32 + qi) * 32 + vcol];
        apv[nt] = __builtin_amdgcn_mfma_f32_32x32x16_bf16(pa, bv, apv[nt], 0, 0, 0);
      }
      __builtin_amdgcn_s_setprio(0);
    }
    if (kc + 1 < 64) { writeK(cur ^ 1); writeV(cur ^ 1); }
    asm volatile("s_waitcnt lgkmcnt(0)" ::: "memory");
    __builtin_amdgcn_s_barrier();
    asm volatile("" ::: "memory");
    cur ^= 1;
  }
  s += __shfl_xor(s, 32);
  if (hi == 0) *sumPtr = -__builtin_amdgcn_logf(s);
  const float rinv = 1.0f / s;
  float invr[16];
#pragma unroll
  for (int r = 0; r < 16; ++r)
    invr[r] = __shfl(rinv, (r & 3) + 8 * (r >> 2) + 4 * hi);
#pragma unroll
  for (int nt = 0; nt < 4; ++nt)
#pragma unroll
    for (int r = 0; r < 16; ++r) {
      const int row = (r & 3) + 8 * (r >> 2) + 4 * hi;
      ctxW[(size_t)row * DD + nt * 32 + qi] = apv[nt][r] * invr[r];
    }
}

__global__ __launch_bounds__(128, 3) void attn_mat(
    const float* __restrict__ q, const float* __restrict__ k, float* out) {
  __shared__ __align__(16) unsigned short kT[2][32 * DD];
  const int tid = threadIdx.x;
  const int w = tid >> 6, l = tid & 63;
  const int qi = l & 31, hi = l >> 5;
  const unsigned swz = (l & 7) << 3;
  const int i0 = blockIdx.x;
  const int b = (i0 & 7) + 8 * (i0 >> 8);
  const int qx = (i0 >> 3) & 31;
  const int qw = qx * 64 + w * 32;
  const float* qb_ = q + (size_t)b * LL * DD;
  const float* kb_ = k + (size_t)b * LL * DD;
  float* attnW = out + (size_t)NB * LL * DD + ((size_t)b * LL + qw) * (size_t)LL;
  const float nlsv = attnW[(size_t)qi * LL + (LL - 1)];
  float nlsr[16];
#pragma unroll
  for (int r = 0; r < 16; ++r)
    nlsr[r] = __shfl(nlsv, (r & 3) + 8 * (r >> 2) + 4 * hi);
  const int kr = tid >> 5, kc4 = tid & 31;
  short8 aq[8];
  {
    const float* qrow = qb_ + (size_t)(qw + qi) * DD + hi * 8;
#pragma unroll
    for (int dt = 0; dt < 8; ++dt) {
      f32x4 x0 = *(const f32x4*)(qrow + dt * 16);
      f32x4 x1 = *(const f32x4*)(qrow + dt * 16 + 4);
      int4v pw = {(int)pkbf(x0[0], x0[1]), (int)pkbf(x0[2], x0[3]),
                  (int)pkbf(x1[0], x1[1]), (int)pkbf(x1[2], x1[3])};
      aq[dt] = __builtin_bit_cast(short8, pw);
    }
  }
  f32x4 pk[8];
  auto loadK = [&](int kc) {
#pragma unroll
    for (int j2 = 0; j2 < 8; ++j2)
      pk[j2] = *(const f32x4*)(kb_ + (size_t)(kc * 32 + kr + 4 * j2) * DD + kc4 * 4);
  };
  auto writeK = [&](int buf) {
#pragma unroll
    for (int j2 = 0; j2 < 8; ++j2) {
      const int r = kr + 4 * j2;
      uint2v y = {pkbf(pk[j2][0], pk[j2][1]), pkbf(pk[j2][2], pk[j2][3])};
      *(uint2v*)&kT[buf][r * DD + ((kc4 * 4) ^ ((r & 7) << 3))] = y;
    }
  };
  loadK(0); writeK(0);
  asm volatile("s_waitcnt lgkmcnt(0)" ::: "memory");
  __builtin_amdgcn_s_barrier();
  asm volatile("" ::: "memory");
  int cur = 0;
  for (int kc = 0; kc < 64; ++kc) {
    if (kc + 1 < 64) loadK(kc + 1);
    f32x16 acc = (f32x16){0.f,0.f,0.f,0.f,0.f,0.f,0.f,0.f,0.f,0.f,0.f,0.f,0.f,0.f,0.f,0.f};
    __builtin_amdgcn_s_setprio(1);
#pragma unroll
    for (int dt = 0; dt < 8; ++dt) {
      short8 ka = *(const short8*)&kT[cur][qi * DD + ((dt * 16 + hi * 8) ^ swz)];
      acc = __builtin_amdgcn_mfma_f32_32x32x16_bf16(aq[dt], ka, acc, 0, 0, 0);
    }
    __builtin_amdgcn_s_setprio(0);
#pragma unroll
    for (int r = 0; r < 16; ++r) {
      const int row = (r & 3) + 8 * (r >> 2) + 4 * hi;
      const float o = __builtin_amdgcn_exp2f(__builtin_fmaf(acc[r], C1, nlsr[r]));
      attnW[(size_t)row * LL + kc * 32 + qi] = o;
    }
    if (kc + 1 < 64) writeK(cur ^ 1);
    asm volatile("s_waitcnt lgkmcnt(0)" ::: "memory");
    __builtin_amdgcn_s_barrier();
    asm volatile("" ::: "memory");
    cur ^= 1;
  }
}

extern "C" void kernel_launch(void* const* d_in, const int* in_sizes, int n_in,
                              void* d_out, int out_size, void* d_ws, size_t ws_size,
                              hipStream_t stream) {
  const float* q = (const float*)d_in[0];
  const float* k = (const float*)d_in[1];
  const float* v = (const float*)d_in[2];
  float* out = (float*)d_out;
  const size_t need = (size_t)2 * NB * LL * DD * sizeof(unsigned short);  // 33.5 MB
  if (ws_size >= need) {
    unsigned short* wsK = (unsigned short*)d_ws;
    unsigned short* wsV = wsK + (size_t)NB * LL * DD;
    convKV<<<dim3(NB * 64), dim3(256), 0, stream>>>(k, v, wsK, wsV);
    attn_fused2<<<dim3(256), dim3(512), 0, stream>>>(q, wsK, wsV, out);
  } else {
    attn_ctx<<<dim3(1024), dim3(128), 0, stream>>>(q, k, v, out);
    attn_mat<<<dim3(1024), dim3(128), 0, stream>>>(q, k, out);
  }
}

// Round 19
// 228.040 us; speedup vs baseline: 1.0170x; 1.0170x over previous
//
#include <hip/hip_runtime.h>
#include <hip/hip_bf16.h>

#define LL 2048
#define DD 128
#define NB 32
#define SCALE 0.08838834764831845f
#define C1 (SCALE * 1.4426950408889634f)   // scale * log2(e)

typedef short short8 __attribute__((ext_vector_type(8)));
typedef float f32x4 __attribute__((ext_vector_type(4)));
typedef float f32x16 __attribute__((ext_vector_type(16)));
typedef int int4v __attribute__((ext_vector_type(4)));
typedef unsigned int uint2v __attribute__((ext_vector_type(2)));

__device__ __forceinline__ unsigned int pkbf(float lo, float hi) {
  __hip_bfloat162 h = __float22bfloat162_rn(make_float2(lo, hi));
  union { __hip_bfloat162 h2; unsigned int u; } c;
  c.h2 = h;
  return c.u;
}

__device__ __forceinline__ void load_lds16(const void* g, void* l) {
  __builtin_amdgcn_global_load_lds(
      (const __attribute__((address_space(1))) unsigned int*)g,
      (__attribute__((address_space(3))) unsigned int*)l, 16, 0, 0);
}

// ============================================================================
// One-shot converter: K / V^T -> bf16 tiles in d_ws.
// Tile = 64 keys x 128 d (16384 B). K: 16-slot swizzle g^(key&15).
// V: [d][key ^ ((d&7)<<3)].
// ============================================================================
__global__ __launch_bounds__(256) void convKV(const float* __restrict__ k,
                                              const float* __restrict__ v,
                                              unsigned short* __restrict__ wsK,
                                              unsigned short* __restrict__ wsV) {
  __shared__ float lt[64][132];
  if (blockIdx.x < NB * 32) {
    const int t = blockIdx.x;
    const float* src = k + (size_t)t * 8192;
    unsigned short* dst = wsK + (size_t)t * 8192;
    const int key = threadIdx.x >> 2, dq = (threadIdx.x & 3) * 32;
    const float* row = src + key * 128 + dq;
    unsigned short* drow = dst + key * 128;
#pragma unroll
    for (int g = 0; g < 4; ++g) {
      f32x4 a = *(const f32x4*)(row + g * 8);
      f32x4 b2 = *(const f32x4*)(row + g * 8 + 4);
      int4v y = {(int)pkbf(a[0], a[1]), (int)pkbf(a[2], a[3]),
                 (int)pkbf(b2[0], b2[1]), (int)pkbf(b2[2], b2[3])};
      const int gi = (((dq >> 3) + g) ^ (key & 15));
      *(int4v*)(drow + gi * 8) = y;
    }
  } else {
    const int t = blockIdx.x - NB * 32;
    const float* src = v + (size_t)t * 8192;
    unsigned short* dst = wsV + (size_t)t * 8192;
    const int key = threadIdx.x >> 2, dq = (threadIdx.x & 3) * 32;
#pragma unroll
    for (int g = 0; g < 8; ++g)
      *(f32x4*)&lt[key][dq + g * 4] = *(const f32x4*)(src + key * 128 + dq + g * 4);
    __syncthreads();
    const int d = threadIdx.x >> 1, kh = (threadIdx.x & 1) * 32;
    unsigned short* drow = dst + d * 64;
#pragma unroll
    for (int g = 0; g < 4; ++g) {
      const int k0 = kh + g * 8;
      int4v y = {(int)pkbf(lt[k0 + 0][d], lt[k0 + 1][d]),
                 (int)pkbf(lt[k0 + 2][d], lt[k0 + 3][d]),
                 (int)pkbf(lt[k0 + 4][d], lt[k0 + 5][d]),
                 (int)pkbf(lt[k0 + 6][d], lt[k0 + 7][d])};
      const int gi = ((k0 >> 3) ^ (d & 7));
      *(int4v*)(drow + gi * 8) = y;
    }
  }
}

// ============================================================================
// Main fused kernel — r16 structure, 512 threads / 128 KB LDS.
// Pass 1: flash, 128-key chunks double-buffered (16 barriers).
// Pass 2: attn write, 256-key halves, counted vmcnt(63) (in-order retirement:
// retires the 8 DMA + pre-DMA stores while keeping 63 newest stores in flight).
// ============================================================================
__global__ __launch_bounds__(512, 2) void attn_fused2(
    const float* __restrict__ q, const unsigned short* __restrict__ wsK,
    const unsigned short* __restrict__ wsV, float* out) {
  __shared__ __align__(16) unsigned short smem[65536];   // 128 KB

  const int tid = threadIdx.x;
  const int w = tid >> 6, l = tid & 63;                  // 8 waves
  const int qi = l & 31, hi = l >> 5;
  const unsigned swzv = (l & 7) << 3;                    // V: 8-slot
  const unsigned swzk = (l & 15) << 3;                   // K: 16-slot

  const int i0 = blockIdx.x;             // 256 blocks, 1 per CU
  const int xcd = i0 & 7, j = i0 >> 3;   // 4 batches per XCD
  const int b = xcd + 8 * (j >> 3);
  const int qx8 = j & 7;
  const int qw = qx8 * 256 + w * 32;     // 8 waves cover 256 q-rows

  const float* qb_ = q + (size_t)b * LL * DD;
  float* ctxW = out + ((size_t)b * LL + qw) * DD;
  float* attnW = out + (size_t)NB * LL * DD + ((size_t)b * LL + qw) * (size_t)LL;

  const char* wsKb = (const char*)wsK + (size_t)b * 32 * 16384;
  const char* wsVb = (const char*)wsV + (size_t)b * 32 * 16384;

  unsigned short* kT0 = smem;            // pass 1: 2 x 32 KB K chunks
  unsigned short* vT0 = smem + 32768;    // pass 1: 2 x 32 KB V chunks

#define STAGE32(srcb, ldsb)                                       \
  {                                                               \
    _Pragma("unroll") for (int i_ = 0; i_ < 4; ++i_) {            \
      const int o_ = i_ * 8192 + w * 1024;                        \
      load_lds16((const char*)(srcb) + o_ + l * 16,               \
                 (char*)(ldsb) + o_);                             \
    }                                                             \
  }

  // ---- Q fragments: lane holds Q[qw+qi][dt*16 + hi*8 + j] ----
  short8 aq[8];
  {
    const float* qrow = qb_ + (size_t)(qw + qi) * DD + hi * 8;
#pragma unroll
    for (int dt = 0; dt < 8; ++dt) {
      f32x4 x0 = *(const f32x4*)(qrow + dt * 16);
      f32x4 x1 = *(const f32x4*)(qrow + dt * 16 + 4);
      int4v pw = {(int)pkbf(x0[0], x0[1]), (int)pkbf(x0[2], x0[3]),
                  (int)pkbf(x1[0], x1[1]), (int)pkbf(x1[2], x1[3])};
      aq[dt] = __builtin_bit_cast(short8, pw);
    }
  }

  float s = 0.f;
  f32x16 apv[4];
#pragma unroll
  for (int nt = 0; nt < 4; ++nt)
    apv[nt] = (f32x16){0.f,0.f,0.f,0.f,0.f,0.f,0.f,0.f,0.f,0.f,0.f,0.f,0.f,0.f,0.f,0.f};

  // =================== pass 1: flash (swapped QK + PV) ===================
  STAGE32(wsKb, (char*)kT0);
  STAGE32(wsVb, (char*)vT0);
  asm volatile("s_waitcnt vmcnt(0)" ::: "memory");
  __builtin_amdgcn_s_barrier();
  asm volatile("" ::: "memory");

  int cur = 0;
  for (int kc = 0; kc < 16; ++kc) {      // 128-key chunks
    if (kc + 1 < 16) {
      STAGE32(wsKb + (kc + 1) * 32768, (char*)(kT0 + (cur ^ 1) * 16384));
      STAGE32(wsVb + (kc + 1) * 32768, (char*)(vT0 + (cur ^ 1) * 16384));
    }
    const unsigned short* kTc = kT0 + cur * 16384;
    const unsigned short* vTc = vT0 + cur * 16384;
#pragma unroll
    for (int t = 0; t < 4; ++t) {        // four 32-key groups per chunk
      const int tile = t >> 1, tt = t & 1;
      f32x16 acc = (f32x16){0.f,0.f,0.f,0.f,0.f,0.f,0.f,0.f,0.f,0.f,0.f,0.f,0.f,0.f,0.f,0.f};
      const int arow = tile * 8192 + (tt * 32 + qi) * DD;
      __builtin_amdgcn_s_setprio(1);
#pragma unroll
      for (int dt = 0; dt < 8; ++dt) {
        short8 ka = *(const short8*)&kTc[arow + ((dt * 16 + hi * 8) ^ swzk)];
        acc = __builtin_amdgcn_mfma_f32_32x32x16_bf16(ka, aq[dt], acc, 0, 0, 0);
      }
      __builtin_amdgcn_s_setprio(0);

      float p[16];
#pragma unroll
      for (int r = 0; r < 16; ++r) {
        p[r] = __builtin_amdgcn_exp2f(acc[r] * C1);   // unnormalized, <= ~500
        s += p[r];
      }

#pragma unroll
      for (int kt2 = 0; kt2 < 2; ++kt2) {
        const int p0 = kt2 * 8;
        unsigned a0 = pkbf(p[p0 + 0], p[p0 + 1]);
        unsigned a1 = pkbf(p[p0 + 2], p[p0 + 3]);
        unsigned b0 = pkbf(p[p0 + 4], p[p0 + 5]);
        unsigned b1 = pkbf(p[p0 + 6], p[p0 + 7]);
        unsigned a0s = (unsigned)__shfl_xor((int)a0, 32);
        unsigned a1s = (unsigned)__shfl_xor((int)a1, 32);
        unsigned b0s = (unsigned)__shfl_xor((int)b0, 32);
        unsigned b1s = (unsigned)__shfl_xor((int)b1, 32);
        unsigned w0 = hi ? b0s : a0;
        unsigned w1 = hi ? b1s : a1;
        unsigned w2 = hi ? b0 : a0s;
        unsigned w3 = hi ? b1 : a1s;
        int4v pw = {(int)w0, (int)w1, (int)w2, (int)w3};
        short8 pa = __builtin_bit_cast(short8, pw);

        const int vbase = tile * 8192;
        const int vc = ((tt * 32 + kt2 * 16 + hi * 8) ^ swzv);
        __builtin_amdgcn_s_setprio(1);
#pragma unroll
        for (int nt = 0; nt < 4; ++nt) {
          short8 bv = *(const short8*)&vTc[vbase + (nt * 32 + qi) * 64 + vc];
          apv[nt] = __builtin_amdgcn_mfma_f32_32x32x16_bf16(pa, bv, apv[nt], 0, 0, 0);
        }
        __builtin_amdgcn_s_setprio(0);
      }
    }
    asm volatile("s_waitcnt vmcnt(0) lgkmcnt(0)" ::: "memory");
    __builtin_amdgcn_s_barrier();
    asm volatile("" ::: "memory");
    cur ^= 1;
  }

  // ---- softmax denominators ----
  s += __shfl_xor(s, 32);                      // denominator for q-row qi
  const float rinv = 1.0f / s;
  const float nls = -__builtin_amdgcn_logf(s); // -log2(sum)
  float nlsr[16], invr[16];
#pragma unroll
  for (int r = 0; r < 16; ++r) {
    const int row = (r & 3) + 8 * (r >> 2) + 4 * hi;
    nlsr[r] = __shfl(nls, row);
    invr[r] = __shfl(rinv, row);
  }

  // =================== pass 2 prologue ===================
  unsigned short* h0 = smem;             // 64 KB half = 256 keys (4 tiles)
  unsigned short* h1 = smem + 32768;

#define STAGE64(c, halfp)                                                    \
  {                                                                          \
    _Pragma("unroll") for (int i_ = 0; i_ < 8; ++i_) {                       \
      const int o_ = i_ * 8192 + w * 1024;                                   \
      load_lds16(wsKb + (size_t)(c) * 65536 + o_ + l * 16,                   \
                 (char*)(halfp) + o_);                                       \
    }                                                                        \
  }

  STAGE64(0, h0);   // DMA hides under the ctx stores below

  // ---- context store (64 stores/thread, issued after the 8 DMA) ----
#pragma unroll
  for (int nt = 0; nt < 4; ++nt)
#pragma unroll
    for (int r = 0; r < 16; ++r) {
      const int row = (r & 3) + 8 * (r >> 2) + 4 * hi;
      ctxW[(size_t)row * DD + nt * 32 + qi] = apv[nt][r] * invr[r];
    }

  // in-order retirement: waiting for the 8 DMA necessarily retires pre-DMA
  // stores; vmcnt(63) (counter max) keeps the 63 newest stores in flight.
  asm volatile("s_waitcnt vmcnt(63) lgkmcnt(0)" ::: "memory");
  __builtin_amdgcn_s_barrier();
  asm volatile("" ::: "memory");

  // =================== pass 2: attn write (normal QK) ===================
  for (int c = 0; c < 8; ++c) {          // 256-key chunks
    unsigned short* curh = (c & 1) ? h1 : h0;
    unsigned short* nxth = (c & 1) ? h0 : h1;
    if (c + 1 < 8) STAGE64(c + 1, nxth);

#pragma unroll
    for (int g = 0; g < 8; ++g) {        // eight 32-key groups per chunk
      const int tile = g >> 1, tt = g & 1;
      const unsigned short* kTc = curh + tile * 8192;
      f32x16 acc = (f32x16){0.f,0.f,0.f,0.f,0.f,0.f,0.f,0.f,0.f,0.f,0.f,0.f,0.f,0.f,0.f,0.f};
      const int arow = (tt * 32 + qi) * DD;
      __builtin_amdgcn_s_setprio(1);
#pragma unroll
      for (int dt = 0; dt < 8; ++dt) {
        short8 ka = *(const short8*)&kTc[arow + ((dt * 16 + hi * 8) ^ swzk)];
        acc = __builtin_amdgcn_mfma_f32_32x32x16_bf16(aq[dt], ka, acc, 0, 0, 0);
      }
      __builtin_amdgcn_s_setprio(0);
      // acc[r]: q-row (r&3)+8*(r>>2)+4*hi, key c*256 + g*32 + qi
      float* dstc = attnW + c * 256 + g * 32 + qi;
#pragma unroll
      for (int r = 0; r < 16; ++r) {
        const int row = (r & 3) + 8 * (r >> 2) + 4 * hi;
        dstc[(size_t)row * LL] =
            __builtin_amdgcn_exp2f(__builtin_fmaf(acc[r], C1, nlsr[r]));
      }
    }

    // vmcnt(63): retires this chunk's 8 DMA (+ any stores older than them)
    // while keeping the 63 newest stores in flight.
    asm volatile("s_waitcnt vmcnt(63) lgkmcnt(0)" ::: "memory");
    __builtin_amdgcn_s_barrier();
    asm volatile("" ::: "memory");
  }
#undef STAGE64
#undef STAGE32
}

// ============================================================================
// Fallback path (round-8, used only if ws_size too small)
// ============================================================================
__global__ __launch_bounds__(128, 2) void attn_ctx(
    const float* __restrict__ q, const float* __restrict__ k,
    const float* __restrict__ v, float* out) {
  __shared__ __align__(16) unsigned short kT[2][32 * DD];
  __shared__ __align__(16) unsigned short vT[2][DD * 32];
  const int tid = threadIdx.x;
  const int w = tid >> 6, l = tid & 63;
  const int qi = l & 31, hi = l >> 5;
  const unsigned swz = (l & 7) << 3;
  const int i0 = blockIdx.x;
  const int b = (i0 & 7) + 8 * (i0 >> 8);
  const int qx = (i0 >> 3) & 31;
  const int qw = qx * 64 + w * 32;
  const float* qb_ = q + (size_t)b * LL * DD;
  const float* kb_ = k + (size_t)b * LL * DD;
  const float* vb_ = v + (size_t)b * LL * DD;
  float* ctxW = out + ((size_t)b * LL + qw) * DD;
  float* sumPtr = out + (size_t)NB * LL * DD + ((size_t)b * LL + qw + qi) * LL + (LL - 1);
  const int kr = tid >> 5, kc4 = tid & 31;
  const int vk0 = (tid & 7) * 4, vd0 = (tid >> 3) * 8;
  short8 aq[8];
  {
    const float* qrow = qb_ + (size_t)(qw + qi) * DD + hi * 8;
#pragma unroll
    for (int dt = 0; dt < 8; ++dt) {
      f32x4 x0 = *(const f32x4*)(qrow + dt * 16);
      f32x4 x1 = *(const f32x4*)(qrow + dt * 16 + 4);
      int4v pw = {(int)pkbf(x0[0], x0[1]), (int)pkbf(x0[2], x0[3]),
                  (int)pkbf(x1[0], x1[1]), (int)pkbf(x1[2], x1[3])};
      aq[dt] = __builtin_bit_cast(short8, pw);
    }
  }
  f32x4 pk[8], pv[8];
  auto loadK = [&](int kc) {
#pragma unroll
    for (int j2 = 0; j2 < 8; ++j2)
      pk[j2] = *(const f32x4*)(kb_ + (size_t)(kc * 32 + kr + 4 * j2) * DD + kc4 * 4);
  };
  auto writeK = [&](int buf) {
#pragma unroll
    for (int j2 = 0; j2 < 8; ++j2) {
      const int r = kr + 4 * j2;
      uint2v y = {pkbf(pk[j2][0], pk[j2][1]), pkbf(pk[j2][2], pk[j2][3])};
      *(uint2v*)&kT[buf][r * DD + ((kc4 * 4) ^ ((r & 7) << 3))] = y;
    }
  };
  auto loadV = [&](int kc) {
#pragma unroll
    for (int i = 0; i < 4; ++i)
#pragma unroll
      for (int h = 0; h < 2; ++h)
        pv[i * 2 + h] = *(const f32x4*)(vb_ + (size_t)(kc * 32 + vk0 + i) * DD + vd0 + h * 4);
  };
  auto writeV = [&](int buf) {
#pragma unroll
    for (int dd = 0; dd < 8; ++dd) {
      const int h = dd >> 2, c = dd & 3;
      const int r = vd0 + dd;
      uint2v y = {pkbf(pv[0 + h][c], pv[2 + h][c]), pkbf(pv[4 + h][c], pv[6 + h][c])};
      *(uint2v*)&vT[buf][r * 32 + (vk0 ^ ((r & 3) << 3))] = y;
    }
  };
  float s = 0.f;
  f32x16 apv[4];
#pragma unroll
  for (int nt = 0; nt < 4; ++nt)
    apv[nt] = (f32x16){0.f,0.f,0.f,0.f,0.f,0.f,0.f,0.f,0.f,0.f,0.f,0.f,0.f,0.f,0.f,0.f};
  loadK(0); loadV(0); writeK(0); writeV(0);
  asm volatile("s_waitcnt lgkmcnt(0)" ::: "memory");
  __builtin_amdgcn_s_barrier();
  asm volatile("" ::: "memory");
  int cur = 0;
  for (int kc = 0; kc < 64; ++kc) {
    if (kc + 1 < 64) { loadK(kc + 1); loadV(kc + 1); }
    f32x16 acc = (f32x16){0.f,0.f,0.f,0.f,0.f,0.f,0.f,0.f,0.f,0.f,0.f,0.f,0.f,0.f,0.f,0.f};
    __builtin_amdgcn_s_setprio(1);
#pragma unroll
    for (int dt = 0; dt < 8; ++dt) {
      short8 ka = *(const short8*)&kT[cur][qi * DD + ((dt * 16 + hi * 8) ^ swz)];
      acc = __builtin_amdgcn_mfma_f32_32x32x16_bf16(ka, aq[dt], acc, 0, 0, 0);
    }
    __builtin_amdgcn_s_setprio(0);
    float p[16];
#pragma unroll
    for (int r = 0; r < 16; ++r) { p[r] = __builtin_amdgcn_exp2f(acc[r] * C1); s += p[r]; }
#pragma unroll
    for (int kt2 = 0; kt2 < 2; ++kt2) {
      const int p0 = kt2 * 8;
      unsigned a0 = pkbf(p[p0 + 0], p[p0 + 1]);
      unsigned a1 = pkbf(p[p0 + 2], p[p0 + 3]);
      unsigned b0 = pkbf(p[p0 + 4], p[p0 + 5]);
      unsigned b1 = pkbf(p[p0 + 6], p[p0 + 7]);
      unsigned a0s = (unsigned)__shfl_xor((int)a0, 32);
      unsigned a1s = (unsigned)__shfl_xor((int)a1, 32);
      unsigned b0s = (unsigned)__shfl_xor((int)b0, 32);
      unsigned b1s = (unsigned)__shfl_xor((int)b1, 32);
      unsigned w0 = hi ? b0s : a0;
      unsigned w1 = hi ? b1s : a1;
      unsigned w2 = hi ? b0 : a0s;
      unsigned w3 = hi ? b1 : a1s;
      int4v pw = {(int)w0, (int)w1, (int)w2, (int)w3};
      short8 pa = __builtin_bit_cast(short8, pw);
      const int vcol = (kt2 * 16 + hi * 8) ^ ((qi & 3) << 3);
      __builtin_amdgcn_s_setprio(1);
#pragma unroll
      for (int nt = 0; nt < 4; ++nt) {
        short8 bv = *(const short8*)&vT[cur][(nt * 32 + qi) * 32 + vcol];
        apv[nt] = __builtin_amdgcn_mfma_f32_32x32x16_bf16(pa, bv, apv[nt], 0, 0, 0);
      }
      __builtin_amdgcn_s_setprio(0);
    }
    if (kc + 1 < 64) { writeK(cur ^ 1); writeV(cur ^ 1); }
    asm volatile("s_waitcnt lgkmcnt(0)" ::: "memory");
    __builtin_amdgcn_s_barrier();
    asm volatile("" ::: "memory");
    cur ^= 1;
  }
  s += __shfl_xor(s, 32);
  if (hi == 0) *sumPtr = -__builtin_amdgcn_logf(s);
  const float rinv = 1.0f / s;
  float invr[16];
#pragma unroll
  for (int r = 0; r < 16; ++r)
    invr[r] = __shfl(rinv, (r & 3) + 8 * (r >> 2) + 4 * hi);
#pragma unroll
  for (int nt = 0; nt < 4; ++nt)
#pragma unroll
    for (int r = 0; r < 16; ++r) {
      const int row = (r & 3) + 8 * (r >> 2) + 4 * hi;
      ctxW[(size_t)row * DD + nt * 32 + qi] = apv[nt][r] * invr[r];
    }
}

__global__ __launch_bounds__(128, 3) void attn_mat(
    const float* __restrict__ q, const float* __restrict__ k, float* out) {
  __shared__ __align__(16) unsigned short kT[2][32 * DD];
  const int tid = threadIdx.x;
  const int w = tid >> 6, l = tid & 63;
  const int qi = l & 31, hi = l >> 5;
  const unsigned swz = (l & 7) << 3;
  const int i0 = blockIdx.x;
  const int b = (i0 & 7) + 8 * (i0 >> 8);
  const int qx = (i0 >> 3) & 31;
  const int qw = qx * 64 + w * 32;
  const float* qb_ = q + (size_t)b * LL * DD;
  const float* kb_ = k + (size_t)b * LL * DD;
  float* attnW = out + (size_t)NB * LL * DD + ((size_t)b * LL + qw) * (size_t)LL;
  const float nlsv = attnW[(size_t)qi * LL + (LL - 1)];
  float nlsr[16];
#pragma unroll
  for (int r = 0; r < 16; ++r)
    nlsr[r] = __shfl(nlsv, (r & 3) + 8 * (r >> 2) + 4 * hi);
  const int kr = tid >> 5, kc4 = tid & 31;
  short8 aq[8];
  {
    const float* qrow = qb_ + (size_t)(qw + qi) * DD + hi * 8;
#pragma unroll
    for (int dt = 0; dt < 8; ++dt) {
      f32x4 x0 = *(const f32x4*)(qrow + dt * 16);
      f32x4 x1 = *(const f32x4*)(qrow + dt * 16 + 4);
      int4v pw = {(int)pkbf(x0[0], x0[1]), (int)pkbf(x0[2], x0[3]),
                  (int)pkbf(x1[0], x1[1]), (int)pkbf(x1[2], x1[3])};
      aq[dt] = __builtin_bit_cast(short8, pw);
    }
  }
  f32x4 pk[8];
  auto loadK = [&](int kc) {
#pragma unroll
    for (int j2 = 0; j2 < 8; ++j2)
      pk[j2] = *(const f32x4*)(kb_ + (size_t)(kc * 32 + kr + 4 * j2) * DD + kc4 * 4);
  };
  auto writeK = [&](int buf) {
#pragma unroll
    for (int j2 = 0; j2 < 8; ++j2) {
      const int r = kr + 4 * j2;
      uint2v y = {pkbf(pk[j2][0], pk[j2][1]), pkbf(pk[j2][2], pk[j2][3])};
      *(uint2v*)&kT[buf][r * DD + ((kc4 * 4) ^ ((r & 7) << 3))] = y;
    }
  };
  loadK(0); writeK(0);
  asm volatile("s_waitcnt lgkmcnt(0)" ::: "memory");
  __builtin_amdgcn_s_barrier();
  asm volatile("" ::: "memory");
  int cur = 0;
  for (int kc = 0; kc < 64; ++kc) {
    if (kc + 1 < 64) loadK(kc + 1);
    f32x16 acc = (f32x16){0.f,0.f,0.f,0.f,0.f,0.f,0.f,0.f,0.f,0.f,0.f,0.f,0.f,0.f,0.f,0.f};
    __builtin_amdgcn_s_setprio(1);
#pragma unroll
    for (int dt = 0; dt < 8; ++dt) {
      short8 ka = *(const short8*)&kT[cur][qi * DD + ((dt * 16 + hi * 8) ^ swz)];
      acc = __builtin_amdgcn_mfma_f32_32x32x16_bf16(aq[dt], ka, acc, 0, 0, 0);
    }
    __builtin_amdgcn_s_setprio(0);
#pragma unroll
    for (int r = 0; r < 16; ++r) {
      const int row = (r & 3) + 8 * (r >> 2) + 4 * hi;
      const float o = __builtin_amdgcn_exp2f(__builtin_fmaf(acc[r], C1, nlsr[r]));
      attnW[(size_t)row * LL + kc * 32 + qi] = o;
    }
    if (kc + 1 < 64) writeK(cur ^ 1);
    asm volatile("s_waitcnt lgkmcnt(0)" ::: "memory");
    __builtin_amdgcn_s_barrier();
    asm volatile("" ::: "memory");
    cur ^= 1;
  }
}

extern "C" void kernel_launch(void* const* d_in, const int* in_sizes, int n_in,
                              void* d_out, int out_size, void* d_ws, size_t ws_size,
                              hipStream_t stream) {
  const float* q = (const float*)d_in[0];
  const float* k = (const float*)d_in[1];
  const float* v = (const float*)d_in[2];
  float* out = (float*)d_out;
  const size_t need = (size_t)2 * NB * LL * DD * sizeof(unsigned short);  // 33.5 MB
  if (ws_size >= need) {
    unsigned short* wsK = (unsigned short*)d_ws;
    unsigned short* wsV = wsK + (size_t)NB * LL * DD;
    convKV<<<dim3(NB * 64), dim3(256), 0, stream>>>(k, v, wsK, wsV);
    attn_fused2<<<dim3(256), dim3(512), 0, stream>>>(q, wsK, wsV, out);
  } else {
    attn_ctx<<<dim3(1024), dim3(128), 0, stream>>>(q, k, v, out);
    attn_mat<<<dim3(1024), dim3(128), 0, stream>>>(q, k, out);
  }
}

// Round 20
// 215.839 us; speedup vs baseline: 1.0745x; 1.0565x over previous
//
#include <hip/hip_runtime.h>
#include <hip/hip_bf16.h>

#define LL 2048
#define DD 128
#define NB 32
#define SCALE 0.08838834764831845f
#define C1 (SCALE * 1.4426950408889634f)   // scale * log2(e)

typedef short short8 __attribute__((ext_vector_type(8)));
typedef float f32x4 __attribute__((ext_vector_type(4)));
typedef float f32x16 __attribute__((ext_vector_type(16)));
typedef int int4v __attribute__((ext_vector_type(4)));
typedef unsigned int uint2v __attribute__((ext_vector_type(2)));

__device__ __forceinline__ unsigned int pkbf(float lo, float hi) {
  __hip_bfloat162 h = __float22bfloat162_rn(make_float2(lo, hi));
  union { __hip_bfloat162 h2; unsigned int u; } c;
  c.h2 = h;
  return c.u;
}

__device__ __forceinline__ void load_lds16(const void* g, void* l) {
  __builtin_amdgcn_global_load_lds(
      (const __attribute__((address_space(1))) unsigned int*)g,
      (__attribute__((address_space(3))) unsigned int*)l, 16, 0, 0);
}

// ============================================================================
// One-shot converter: K / V^T -> bf16 tiles in d_ws.
// Tile = 64 keys x 128 d (16384 B). K: 16-slot swizzle g^(key&15).
// V: [d][key ^ ((d&7)<<3)].
// ============================================================================
__global__ __launch_bounds__(256) void convKV(const float* __restrict__ k,
                                              const float* __restrict__ v,
                                              unsigned short* __restrict__ wsK,
                                              unsigned short* __restrict__ wsV) {
  __shared__ float lt[64][132];
  if (blockIdx.x < NB * 32) {
    const int t = blockIdx.x;
    const float* src = k + (size_t)t * 8192;
    unsigned short* dst = wsK + (size_t)t * 8192;
    const int key = threadIdx.x >> 2, dq = (threadIdx.x & 3) * 32;
    const float* row = src + key * 128 + dq;
    unsigned short* drow = dst + key * 128;
#pragma unroll
    for (int g = 0; g < 4; ++g) {
      f32x4 a = *(const f32x4*)(row + g * 8);
      f32x4 b2 = *(const f32x4*)(row + g * 8 + 4);
      int4v y = {(int)pkbf(a[0], a[1]), (int)pkbf(a[2], a[3]),
                 (int)pkbf(b2[0], b2[1]), (int)pkbf(b2[2], b2[3])};
      const int gi = (((dq >> 3) + g) ^ (key & 15));
      *(int4v*)(drow + gi * 8) = y;
    }
  } else {
    const int t = blockIdx.x - NB * 32;
    const float* src = v + (size_t)t * 8192;
    unsigned short* dst = wsV + (size_t)t * 8192;
    const int key = threadIdx.x >> 2, dq = (threadIdx.x & 3) * 32;
#pragma unroll
    for (int g = 0; g < 8; ++g)
      *(f32x4*)&lt[key][dq + g * 4] = *(const f32x4*)(src + key * 128 + dq + g * 4);
    __syncthreads();
    const int d = threadIdx.x >> 1, kh = (threadIdx.x & 1) * 32;
    unsigned short* drow = dst + d * 64;
#pragma unroll
    for (int g = 0; g < 4; ++g) {
      const int k0 = kh + g * 8;
      int4v y = {(int)pkbf(lt[k0 + 0][d], lt[k0 + 1][d]),
                 (int)pkbf(lt[k0 + 2][d], lt[k0 + 3][d]),
                 (int)pkbf(lt[k0 + 4][d], lt[k0 + 5][d]),
                 (int)pkbf(lt[k0 + 6][d], lt[k0 + 7][d])};
      const int gi = ((k0 >> 3) ^ (d & 7));
      *(int4v*)(drow + gi * 8) = y;
    }
  }
}

// ============================================================================
// Main fused kernel — r16 structure, 512 threads / 128 KB LDS.
// Pass 1: flash, 128-key chunks double-buffered (16 barriers).
// Pass 2: attn write, 256-key halves, counted vmcnt(63).
// Output stores (attn + ctx) are NONTEMPORAL: each instruction covers one
// full aligned 128B line (32 lanes x 4B) -> no amplification risk (unlike
// r3's 16B scatter), and the 537MB write-once stream stops evicting K from L2.
// ============================================================================
__global__ __launch_bounds__(512, 2) void attn_fused2(
    const float* __restrict__ q, const unsigned short* __restrict__ wsK,
    const unsigned short* __restrict__ wsV, float* out) {
  __shared__ __align__(16) unsigned short smem[65536];   // 128 KB

  const int tid = threadIdx.x;
  const int w = tid >> 6, l = tid & 63;                  // 8 waves
  const int qi = l & 31, hi = l >> 5;
  const unsigned swzv = (l & 7) << 3;                    // V: 8-slot
  const unsigned swzk = (l & 15) << 3;                   // K: 16-slot

  const int i0 = blockIdx.x;             // 256 blocks, 1 per CU
  const int xcd = i0 & 7, j = i0 >> 3;   // 4 batches per XCD
  const int b = xcd + 8 * (j >> 3);
  const int qx8 = j & 7;
  const int qw = qx8 * 256 + w * 32;     // 8 waves cover 256 q-rows

  const float* qb_ = q + (size_t)b * LL * DD;
  float* ctxW = out + ((size_t)b * LL + qw) * DD;
  float* attnW = out + (size_t)NB * LL * DD + ((size_t)b * LL + qw) * (size_t)LL;

  const char* wsKb = (const char*)wsK + (size_t)b * 32 * 16384;
  const char* wsVb = (const char*)wsV + (size_t)b * 32 * 16384;

  unsigned short* kT0 = smem;            // pass 1: 2 x 32 KB K chunks
  unsigned short* vT0 = smem + 32768;    // pass 1: 2 x 32 KB V chunks

#define STAGE32(srcb, ldsb)                                       \
  {                                                               \
    _Pragma("unroll") for (int i_ = 0; i_ < 4; ++i_) {            \
      const int o_ = i_ * 8192 + w * 1024;                        \
      load_lds16((const char*)(srcb) + o_ + l * 16,               \
                 (char*)(ldsb) + o_);                             \
    }                                                             \
  }

  // ---- Q fragments: lane holds Q[qw+qi][dt*16 + hi*8 + j] ----
  short8 aq[8];
  {
    const float* qrow = qb_ + (size_t)(qw + qi) * DD + hi * 8;
#pragma unroll
    for (int dt = 0; dt < 8; ++dt) {
      f32x4 x0 = *(const f32x4*)(qrow + dt * 16);
      f32x4 x1 = *(const f32x4*)(qrow + dt * 16 + 4);
      int4v pw = {(int)pkbf(x0[0], x0[1]), (int)pkbf(x0[2], x0[3]),
                  (int)pkbf(x1[0], x1[1]), (int)pkbf(x1[2], x1[3])};
      aq[dt] = __builtin_bit_cast(short8, pw);
    }
  }

  float s = 0.f;
  f32x16 apv[4];
#pragma unroll
  for (int nt = 0; nt < 4; ++nt)
    apv[nt] = (f32x16){0.f,0.f,0.f,0.f,0.f,0.f,0.f,0.f,0.f,0.f,0.f,0.f,0.f,0.f,0.f,0.f};

  // =================== pass 1: flash (swapped QK + PV) ===================
  STAGE32(wsKb, (char*)kT0);
  STAGE32(wsVb, (char*)vT0);
  asm volatile("s_waitcnt vmcnt(0)" ::: "memory");
  __builtin_amdgcn_s_barrier();
  asm volatile("" ::: "memory");

  int cur = 0;
  for (int kc = 0; kc < 16; ++kc) {      // 128-key chunks
    if (kc + 1 < 16) {
      STAGE32(wsKb + (kc + 1) * 32768, (char*)(kT0 + (cur ^ 1) * 16384));
      STAGE32(wsVb + (kc + 1) * 32768, (char*)(vT0 + (cur ^ 1) * 16384));
    }
    const unsigned short* kTc = kT0 + cur * 16384;
    const unsigned short* vTc = vT0 + cur * 16384;
#pragma unroll
    for (int t = 0; t < 4; ++t) {        // four 32-key groups per chunk
      const int tile = t >> 1, tt = t & 1;
      f32x16 acc = (f32x16){0.f,0.f,0.f,0.f,0.f,0.f,0.f,0.f,0.f,0.f,0.f,0.f,0.f,0.f,0.f,0.f};
      const int arow = tile * 8192 + (tt * 32 + qi) * DD;
      __builtin_amdgcn_s_setprio(1);
#pragma unroll
      for (int dt = 0; dt < 8; ++dt) {
        short8 ka = *(const short8*)&kTc[arow + ((dt * 16 + hi * 8) ^ swzk)];
        acc = __builtin_amdgcn_mfma_f32_32x32x16_bf16(ka, aq[dt], acc, 0, 0, 0);
      }
      __builtin_amdgcn_s_setprio(0);

      float p[16];
#pragma unroll
      for (int r = 0; r < 16; ++r) {
        p[r] = __builtin_amdgcn_exp2f(acc[r] * C1);   // unnormalized, <= ~500
        s += p[r];
      }

#pragma unroll
      for (int kt2 = 0; kt2 < 2; ++kt2) {
        const int p0 = kt2 * 8;
        unsigned a0 = pkbf(p[p0 + 0], p[p0 + 1]);
        unsigned a1 = pkbf(p[p0 + 2], p[p0 + 3]);
        unsigned b0 = pkbf(p[p0 + 4], p[p0 + 5]);
        unsigned b1 = pkbf(p[p0 + 6], p[p0 + 7]);
        unsigned a0s = (unsigned)__shfl_xor((int)a0, 32);
        unsigned a1s = (unsigned)__shfl_xor((int)a1, 32);
        unsigned b0s = (unsigned)__shfl_xor((int)b0, 32);
        unsigned b1s = (unsigned)__shfl_xor((int)b1, 32);
        unsigned w0 = hi ? b0s : a0;
        unsigned w1 = hi ? b1s : a1;
        unsigned w2 = hi ? b0 : a0s;
        unsigned w3 = hi ? b1 : a1s;
        int4v pw = {(int)w0, (int)w1, (int)w2, (int)w3};
        short8 pa = __builtin_bit_cast(short8, pw);

        const int vbase = tile * 8192;
        const int vc = ((tt * 32 + kt2 * 16 + hi * 8) ^ swzv);
        __builtin_amdgcn_s_setprio(1);
#pragma unroll
        for (int nt = 0; nt < 4; ++nt) {
          short8 bv = *(const short8*)&vTc[vbase + (nt * 32 + qi) * 64 + vc];
          apv[nt] = __builtin_amdgcn_mfma_f32_32x32x16_bf16(pa, bv, apv[nt], 0, 0, 0);
        }
        __builtin_amdgcn_s_setprio(0);
      }
    }
    asm volatile("s_waitcnt vmcnt(0) lgkmcnt(0)" ::: "memory");
    __builtin_amdgcn_s_barrier();
    asm volatile("" ::: "memory");
    cur ^= 1;
  }

  // ---- softmax denominators ----
  s += __shfl_xor(s, 32);                      // denominator for q-row qi
  const float rinv = 1.0f / s;
  const float nls = -__builtin_amdgcn_logf(s); // -log2(sum)
  float nlsr[16], invr[16];
#pragma unroll
  for (int r = 0; r < 16; ++r) {
    const int row = (r & 3) + 8 * (r >> 2) + 4 * hi;
    nlsr[r] = __shfl(nls, row);
    invr[r] = __shfl(rinv, row);
  }

  // =================== pass 2 prologue ===================
  unsigned short* h0 = smem;             // 64 KB half = 256 keys (4 tiles)
  unsigned short* h1 = smem + 32768;

#define STAGE64(c, halfp)                                                    \
  {                                                                          \
    _Pragma("unroll") for (int i_ = 0; i_ < 8; ++i_) {                       \
      const int o_ = i_ * 8192 + w * 1024;                                   \
      load_lds16(wsKb + (size_t)(c) * 65536 + o_ + l * 16,                   \
                 (char*)(halfp) + o_);                                       \
    }                                                                        \
  }

  STAGE64(0, h0);   // DMA hides under the ctx stores below

  // ---- context store (nontemporal full-line: 32 lanes x 4B per row) ----
#pragma unroll
  for (int nt = 0; nt < 4; ++nt)
#pragma unroll
    for (int r = 0; r < 16; ++r) {
      const int row = (r & 3) + 8 * (r >> 2) + 4 * hi;
      __builtin_nontemporal_store(apv[nt][r] * invr[r],
                                  ctxW + (size_t)row * DD + nt * 32 + qi);
    }

  // in-order retirement: waiting retires the 8 DMA + pre-DMA stores;
  // vmcnt(63) keeps the 63 newest stores in flight.
  asm volatile("s_waitcnt vmcnt(63) lgkmcnt(0)" ::: "memory");
  __builtin_amdgcn_s_barrier();
  asm volatile("" ::: "memory");

  // =================== pass 2: attn write (normal QK) ===================
  for (int c = 0; c < 8; ++c) {          // 256-key chunks
    unsigned short* curh = (c & 1) ? h1 : h0;
    unsigned short* nxth = (c & 1) ? h0 : h1;
    if (c + 1 < 8) STAGE64(c + 1, nxth);

#pragma unroll
    for (int g = 0; g < 8; ++g) {        // eight 32-key groups per chunk
      const int tile = g >> 1, tt = g & 1;
      const unsigned short* kTc = curh + tile * 8192;
      f32x16 acc = (f32x16){0.f,0.f,0.f,0.f,0.f,0.f,0.f,0.f,0.f,0.f,0.f,0.f,0.f,0.f,0.f,0.f};
      const int arow = (tt * 32 + qi) * DD;
      __builtin_amdgcn_s_setprio(1);
#pragma unroll
      for (int dt = 0; dt < 8; ++dt) {
        short8 ka = *(const short8*)&kTc[arow + ((dt * 16 + hi * 8) ^ swzk)];
        acc = __builtin_amdgcn_mfma_f32_32x32x16_bf16(aq[dt], ka, acc, 0, 0, 0);
      }
      __builtin_amdgcn_s_setprio(0);
      // acc[r]: q-row (r&3)+8*(r>>2)+4*hi, key c*256 + g*32 + qi
      float* dstc = attnW + c * 256 + g * 32 + qi;
#pragma unroll
      for (int r = 0; r < 16; ++r) {
        const int row = (r & 3) + 8 * (r >> 2) + 4 * hi;
        __builtin_nontemporal_store(
            __builtin_amdgcn_exp2f(__builtin_fmaf(acc[r], C1, nlsr[r])),
            dstc + (size_t)row * LL);
      }
    }

    // vmcnt(63): retires this chunk's 8 DMA (+ older stores) while keeping
    // the 63 newest stores in flight.
    asm volatile("s_waitcnt vmcnt(63) lgkmcnt(0)" ::: "memory");
    __builtin_amdgcn_s_barrier();
    asm volatile("" ::: "memory");
  }
#undef STAGE64
#undef STAGE32
}

// ============================================================================
// Fallback path (round-8, used only if ws_size too small)
// ============================================================================
__global__ __launch_bounds__(128, 2) void attn_ctx(
    const float* __restrict__ q, const float* __restrict__ k,
    const float* __restrict__ v, float* out) {
  __shared__ __align__(16) unsigned short kT[2][32 * DD];
  __shared__ __align__(16) unsigned short vT[2][DD * 32];
  const int tid = threadIdx.x;
  const int w = tid >> 6, l = tid & 63;
  const int qi = l & 31, hi = l >> 5;
  const unsigned swz = (l & 7) << 3;
  const int i0 = blockIdx.x;
  const int b = (i0 & 7) + 8 * (i0 >> 8);
  const int qx = (i0 >> 3) & 31;
  const int qw = qx * 64 + w * 32;
  const float* qb_ = q + (size_t)b * LL * DD;
  const float* kb_ = k + (size_t)b * LL * DD;
  const float* vb_ = v + (size_t)b * LL * DD;
  float* ctxW = out + ((size_t)b * LL + qw) * DD;
  float* sumPtr = out + (size_t)NB * LL * DD + ((size_t)b * LL + qw + qi) * LL + (LL - 1);
  const int kr = tid >> 5, kc4 = tid & 31;
  const int vk0 = (tid & 7) * 4, vd0 = (tid >> 3) * 8;
  short8 aq[8];
  {
    const float* qrow = qb_ + (size_t)(qw + qi) * DD + hi * 8;
#pragma unroll
    for (int dt = 0; dt < 8; ++dt) {
      f32x4 x0 = *(const f32x4*)(qrow + dt * 16);
      f32x4 x1 = *(const f32x4*)(qrow + dt * 16 + 4);
      int4v pw = {(int)pkbf(x0[0], x0[1]), (int)pkbf(x0[2], x0[3]),
                  (int)pkbf(x1[0], x1[1]), (int)pkbf(x1[2], x1[3])};
      aq[dt] = __builtin_bit_cast(short8, pw);
    }
  }
  f32x4 pk[8], pv[8];
  auto loadK = [&](int kc) {
#pragma unroll
    for (int j2 = 0; j2 < 8; ++j2)
      pk[j2] = *(const f32x4*)(kb_ + (size_t)(kc * 32 + kr + 4 * j2) * DD + kc4 * 4);
  };
  auto writeK = [&](int buf) {
#pragma unroll
    for (int j2 = 0; j2 < 8; ++j2) {
      const int r = kr + 4 * j2;
      uint2v y = {pkbf(pk[j2][0], pk[j2][1]), pkbf(pk[j2][2], pk[j2][3])};
      *(uint2v*)&kT[buf][r * DD + ((kc4 * 4) ^ ((r & 7) << 3))] = y;
    }
  };
  auto loadV = [&](int kc) {
#pragma unroll
    for (int i = 0; i < 4; ++i)
#pragma unroll
      for (int h = 0; h < 2; ++h)
        pv[i * 2 + h] = *(const f32x4*)(vb_ + (size_t)(kc * 32 + vk0 + i) * DD + vd0 + h * 4);
  };
  auto writeV = [&](int buf) {
#pragma unroll
    for (int dd = 0; dd < 8; ++dd) {
      const int h = dd >> 2, c = dd & 3;
      const int r = vd0 + dd;
      uint2v y = {pkbf(pv[0 + h][c], pv[2 + h][c]), pkbf(pv[4 + h][c], pv[6 + h][c])};
      *(uint2v*)&vT[buf][r * 32 + (vk0 ^ ((r & 3) << 3))] = y;
    }
  };
  float s = 0.f;
  f32x16 apv[4];
#pragma unroll
  for (int nt = 0; nt < 4; ++nt)
    apv[nt] = (f32x16){0.f,0.f,0.f,0.f,0.f,0.f,0.f,0.f,0.f,0.f,0.f,0.f,0.f,0.f,0.f,0.f};
  loadK(0); loadV(0); writeK(0); writeV(0);
  asm volatile("s_waitcnt lgkmcnt(0)" ::: "memory");
  __builtin_amdgcn_s_barrier();
  asm volatile("" ::: "memory");
  int cur = 0;
  for (int kc = 0; kc < 64; ++kc) {
    if (kc + 1 < 64) { loadK(kc + 1); loadV(kc + 1); }
    f32x16 acc = (f32x16){0.f,0.f,0.f,0.f,0.f,0.f,0.f,0.f,0.f,0.f,0.f,0.f,0.f,0.f,0.f,0.f};
    __builtin_amdgcn_s_setprio(1);
#pragma unroll
    for (int dt = 0; dt < 8; ++dt) {
      short8 ka = *(const short8*)&kT[cur][qi * DD + ((dt * 16 + hi * 8) ^ swz)];
      acc = __builtin_amdgcn_mfma_f32_32x32x16_bf16(ka, aq[dt], acc, 0, 0, 0);
    }
    __builtin_amdgcn_s_setprio(0);
    float p[16];
#pragma unroll
    for (int r = 0; r < 16; ++r) { p[r] = __builtin_amdgcn_exp2f(acc[r] * C1); s += p[r]; }
#pragma unroll
    for (int kt2 = 0; kt2 < 2; ++kt2) {
      const int p0 = kt2 * 8;
      unsigned a0 = pkbf(p[p0 + 0], p[p0 + 1]);
      unsigned a1 = pkbf(p[p0 + 2], p[p0 + 3]);
      unsigned b0 = pkbf(p[p0 + 4], p[p0 + 5]);
      unsigned b1 = pkbf(p[p0 + 6], p[p0 + 7]);
      unsigned a0s = (unsigned)__shfl_xor((int)a0, 32);
      unsigned a1s = (unsigned)__shfl_xor((int)a1, 32);
      unsigned b0s = (unsigned)__shfl_xor((int)b0, 32);
      unsigned b1s = (unsigned)__shfl_xor((int)b1, 32);
      unsigned w0 = hi ? b0s : a0;
      unsigned w1 = hi ? b1s : a1;
      unsigned w2 = hi ? b0 : a0s;
      unsigned w3 = hi ? b1 : a1s;
      int4v pw = {(int)w0, (int)w1, (int)w2, (int)w3};
      short8 pa = __builtin_bit_cast(short8, pw);
      const int vcol = (kt2 * 16 + hi * 8) ^ ((qi & 3) << 3);
      __builtin_amdgcn_s_setprio(1);
#pragma unroll
      for (int nt = 0; nt < 4; ++nt) {
        short8 bv = *(const short8*)&vT[cur][(nt * 32 + qi) * 32 + vcol];
        apv[nt] = __builtin_amdgcn_mfma_f32_32x32x16_bf16(pa, bv, apv[nt], 0, 0, 0);
      }
      __builtin_amdgcn_s_setprio(0);
    }
    if (kc + 1 < 64) { writeK(cur ^ 1); writeV(cur ^ 1); }
    asm volatile("s_waitcnt lgkmcnt(0)" ::: "memory");
    __builtin_amdgcn_s_barrier();
    asm volatile("" ::: "memory");
    cur ^= 1;
  }
  s += __shfl_xor(s, 32);
  if (hi == 0) *sumPtr = -__builtin_amdgcn_logf(s);
  const float rinv = 1.0f / s;
  float invr[16];
#pragma unroll
  for (int r = 0; r < 16; ++r)
    invr[r] = __shfl(rinv, (r & 3) + 8 * (r >> 2) + 4 * hi);
#pragma unroll
  for (int nt = 0; nt < 4; ++nt)
#pragma unroll
    for (int r = 0; r < 16; ++r) {
      const int row = (r & 3) + 8 * (r >> 2) + 4 * hi;
      ctxW[(size_t)row * DD + nt * 32 + qi] = apv[nt][r] * invr[r];
    }
}

__global__ __launch_bounds__(128, 3) void attn_mat(
    const float* __restrict__ q, const float* __restrict__ k, float* out) {
  __shared__ __align__(16) unsigned short kT[2][32 * DD];
  const int tid = threadIdx.x;
  const int w = tid >> 6, l = tid & 63;
  const int qi = l & 31, hi = l >> 5;
  const unsigned swz = (l & 7) << 3;
  const int i0 = blockIdx.x;
  const int b = (i0 & 7) + 8 * (i0 >> 8);
  const int qx = (i0 >> 3) & 31;
  const int qw = qx * 64 + w * 32;
  const float* qb_ = q + (size_t)b * LL * DD;
  const float* kb_ = k + (size_t)b * LL * DD;
  float* attnW = out + (size_t)NB * LL * DD + ((size_t)b * LL + qw) * (size_t)LL;
  const float nlsv = attnW[(size_t)qi * LL + (LL - 1)];
  float nlsr[16];
#pragma unroll
  for (int r = 0; r < 16; ++r)
    nlsr[r] = __shfl(nlsv, (r & 3) + 8 * (r >> 2) + 4 * hi);
  const int kr = tid >> 5, kc4 = tid & 31;
  short8 aq[8];
  {
    const float* qrow = qb_ + (size_t)(qw + qi) * DD + hi * 8;
#pragma unroll
    for (int dt = 0; dt < 8; ++dt) {
      f32x4 x0 = *(const f32x4*)(qrow + dt * 16);
      f32x4 x1 = *(const f32x4*)(qrow + dt * 16 + 4);
      int4v pw = {(int)pkbf(x0[0], x0[1]), (int)pkbf(x0[2], x0[3]),
                  (int)pkbf(x1[0], x1[1]), (int)pkbf(x1[2], x1[3])};
      aq[dt] = __builtin_bit_cast(short8, pw);
    }
  }
  f32x4 pk[8];
  auto loadK = [&](int kc) {
#pragma unroll
    for (int j2 = 0; j2 < 8; ++j2)
      pk[j2] = *(const f32x4*)(kb_ + (size_t)(kc * 32 + kr + 4 * j2) * DD + kc4 * 4);
  };
  auto writeK = [&](int buf) {
#pragma unroll
    for (int j2 = 0; j2 < 8; ++j2) {
      const int r = kr + 4 * j2;
      uint2v y = {pkbf(pk[j2][0], pk[j2][1]), pkbf(pk[j2][2], pk[j2][3])};
      *(uint2v*)&kT[buf][r * DD + ((kc4 * 4) ^ ((r & 7) << 3))] = y;
    }
  };
  loadK(0); writeK(0);
  asm volatile("s_waitcnt lgkmcnt(0)" ::: "memory");
  __builtin_amdgcn_s_barrier();
  asm volatile("" ::: "memory");
  int cur = 0;
  for (int kc = 0; kc < 64; ++kc) {
    if (kc + 1 < 64) loadK(kc + 1);
    f32x16 acc = (f32x16){0.f,0.f,0.f,0.f,0.f,0.f,0.f,0.f,0.f,0.f,0.f,0.f,0.f,0.f,0.f,0.f};
    __builtin_amdgcn_s_setprio(1);
#pragma unroll
    for (int dt = 0; dt < 8; ++dt) {
      short8 ka = *(const short8*)&kT[cur][qi * DD + ((dt * 16 + hi * 8) ^ swz)];
      acc = __builtin_amdgcn_mfma_f32_32x32x16_bf16(aq[dt], ka, acc, 0, 0, 0);
    }
    __builtin_amdgcn_s_setprio(0);
#pragma unroll
    for (int r = 0; r < 16; ++r) {
      const int row = (r & 3) + 8 * (r >> 2) + 4 * hi;
      const float o = __builtin_amdgcn_exp2f(__builtin_fmaf(acc[r], C1, nlsr[r]));
      attnW[(size_t)row * LL + kc * 32 + qi] = o;
    }
    if (kc + 1 < 64) writeK(cur ^ 1);
    asm volatile("s_waitcnt lgkmcnt(0)" ::: "memory");
    __builtin_amdgcn_s_barrier();
    asm volatile("" ::: "memory");
    cur ^= 1;
  }
}

extern "C" void kernel_launch(void* const* d_in, const int* in_sizes, int n_in,
                              void* d_out, int out_size, void* d_ws, size_t ws_size,
                              hipStream_t stream) {
  const float* q = (const float*)d_in[0];
  const float* k = (const float*)d_in[1];
  const float* v = (const float*)d_in[2];
  float* out = (float*)d_out;
  const size_t need = (size_t)2 * NB * LL * DD * sizeof(unsigned short);  // 33.5 MB
  if (ws_size >= need) {
    unsigned short* wsK = (unsigned short*)d_ws;
    unsigned short* wsV = wsK + (size_t)NB * LL * DD;
    convKV<<<dim3(NB * 64), dim3(256), 0, stream>>>(k, v, wsK, wsV);
    attn_fused2<<<dim3(256), dim3(512), 0, stream>>>(q, wsK, wsV, out);
  } else {
    attn_ctx<<<dim3(1024), dim3(128), 0, stream>>>(q, k, v, out);
    attn_mat<<<dim3(1024), dim3(128), 0, stream>>>(q, k, out);
  }
}